// Round 12
// baseline (225.979 us; speedup 1.0000x reference)
//
#include <hip/hip_runtime.h>
#include <math.h>

// EGNN fused kernel, round 12: weights in LDS -> 4 waves/SIMD.
// r11 proved no-spill but 2 waves/SIMD leaves 48% stall (issue=52%). The
// register-resident weights ARE the occupancy wall (r3-r10: regs/wave =
// 2048/wavesPerSIMD/4; weights need 112 arch regs -> 2/SIMD). Fix: We2/Wx1/Wx2
// live in LDS (96KB, bf16 col-major, XOR-8 k-swizzle -> ~2-way conflicts);
// only GEMM1's We1 frag (8 regs) stays in registers. 1024 thr = 16 waves,
// wave (jh,ug) owns 32 rows x 16 cols; __launch_bounds__(1024,4) = 4 w/SIMD.
// Phase flow = r9 (4 barriers/tile): ph1 GEMM1(F)->P1 | ph2 GEMM2->macc,mask,
// ->P2, e-partials(butterfly) | ph3 stage t+1, e-final+m_i (macc dies),
// GEMM3(P2)->P1 | ph4 GEMM4(P1)->racc, phi+shift per-thread (linear in cols).

#define BB    2
#define NN    512
#define HDIM  64
#define UDIM  128
#define JT    64
#define NTILE (NN / JT)
#define FP    72    // F row pitch (ushort), 144B
#define PP    136   // P row pitch (ushort), 272B
#define NW    16

typedef float f32x4 __attribute__((ext_vector_type(4)));
typedef short s16x8 __attribute__((ext_vector_type(8)));

__device__ __forceinline__ ushort f2bf(float f) {
    union { float f; unsigned u; } v; v.f = f;
    return (ushort)((v.u + 0x7FFFu + ((v.u >> 16) & 1u)) >> 16);
}
__device__ __forceinline__ unsigned pk2(float lo, float hi) {
    unsigned r;
    asm("v_cvt_pk_bf16_f32 %0, %1, %2" : "=v"(r) : "v"(lo), "v"(hi));
    return r;
}
__device__ __forceinline__ ushort f2bf1(float a) { return (ushort)pk2(a, a); }
__device__ __forceinline__ f32x4 MFMA(s16x8 a, s16x8 b, f32x4 c) {
    return __builtin_amdgcn_mfma_f32_16x16x32_bf16(a, b, c, 0, 0, 0);
}
__device__ __forceinline__ float eluf(float v) { return v > 0.f ? v : __expf(v) - 1.f; }

// B-frag from LDS weights: col-major, k-swizzled (k ^ ((col&15)<<3)).
// Lane (l15,q), k-step s: 8 contiguous k at 32s+8q (8-aligned; XOR flips
// bits>=3 only -> contiguity & 16B alignment preserved).
__device__ __forceinline__ s16x8 wfrag(const ushort* __restrict__ WL, int uc, int s, int q) {
    return *(const s16x8*)(WL + uc * 128 + ((32 * s + 8 * q) ^ ((uc & 15) << 3)));
}

// acc[m] += A[jrb+16m+l15][k] * B[k][uc], K = 32*KS
template <int KS>
__device__ __forceinline__ void gemm_ldsB(const ushort* __restrict__ P, int pitch,
                                          const ushort* __restrict__ WL,
                                          int uc, int l15, int q, int jrb, f32x4 (&acc)[2]) {
    __builtin_amdgcn_s_setprio(1);
#pragma unroll
    for (int s = 0; s < KS; ++s) {
        const s16x8 bf = wfrag(WL, uc, s, q);
        const s16x8 a0 = *(const s16x8*)(P + (jrb + l15) * pitch + 32 * s + 8 * q);
        const s16x8 a1 = *(const s16x8*)(P + (jrb + 16 + l15) * pitch + 32 * s + 8 * q);
        acc[0] = MFMA(a0, bf, acc[0]);
        acc[1] = MFMA(a1, bf, acc[1]);
    }
    __builtin_amdgcn_s_setprio(0);
}

template <bool ELU>
__device__ __forceinline__ void store1(ushort* __restrict__ P, const f32x4 (&v)[2],
                                       int q, int uc, int jrb) {
#pragma unroll
    for (int m = 0; m < 2; ++m)
#pragma unroll
        for (int r = 0; r < 4; ++r) {
            float a = v[m][r];
            if (ELU) a = eluf(a);
            P[(jrb + 16 * m + 4 * q + r) * PP + uc] = f2bf1(a);
        }
}

__global__ __launch_bounds__(1024, 4) void egnn_lds16(
    const float* __restrict__ x, const float* __restrict__ h,
    const float* __restrict__ We1, const float* __restrict__ be1,
    const float* __restrict__ We2, const float* __restrict__ be2,
    const float* __restrict__ Winf, const float* __restrict__ binf,
    const float* __restrict__ Wx1, const float* __restrict__ bx1,
    const float* __restrict__ Wx2, const float* __restrict__ bx2,
    const float* __restrict__ Wx3, const float* __restrict__ bx3,
    const float* __restrict__ Wh1, const float* __restrict__ bh1,
    const float* __restrict__ Wh2, const float* __restrict__ bh2,
    const float* __restrict__ Wout, const float* __restrict__ bout,
    float* __restrict__ out) {
    __shared__ ushort W2L[UDIM * UDIM];   // We2, 32KB
    __shared__ ushort W3L[UDIM * UDIM];   // Wx1
    __shared__ ushort W4L[UDIM * UDIM];   // Wx2
    __shared__ ushort F[JT][FP];          // feat tile (single-buffered)
    __shared__ ushort P1[JT][PP];
    __shared__ ushort P2[JT][PP];
    __shared__ float normL[2][JT];
    __shared__ float diffL[2][JT][3];
    __shared__ float rpartE[8][JT];
    __shared__ float bias1L[UDIM];
    __shared__ float miL[2][UDIM];
    __shared__ float shiftL[NW][3];
    __shared__ float catL[UDIM + HDIM];
    __shared__ float th1[UDIM], th2[UDIM];

    const int bi = blockIdx.x;
    const int b  = bi >> 9;
    const int i  = bi & (NN - 1);
    const int tid  = threadIdx.x;
    const int lane = tid & 63;
    const int w    = tid >> 6;        // 0..15
    const int ug   = w & 7;           // col group: [16ug, 16ug+16)
    const int jh   = w >> 3;          // row half: [32jh, 32jh+32)
    const int l15  = lane & 15;
    const int q    = lane >> 4;
    const int uc   = 16 * ug + l15;   // this lane's column
    const int jrb  = 32 * jh;         // local row base

    // ---- stage weights -> LDS (bf16, col-major, swizzled) ----
    for (int idx = tid; idx < UDIM * UDIM; idx += 1024) {
        const int k = idx >> 7, col = idx & 127;
        const int off = col * 128 + (k ^ ((col & 15) << 3));
        W2L[off] = f2bf(We2[idx]);
        W3L[off] = f2bf(Wx1[idx]);
        W4L[off] = f2bf(Wx2[idx]);
    }
    // GEMM1 B-frag in registers (8 VGPRs)
    s16x8 wB1[2];
#pragma unroll
    for (int s = 0; s < 2; ++s) {
        s16x8 r;
#pragma unroll
        for (int ii = 0; ii < 8; ++ii)
            r[ii] = (short)f2bf(We1[(1 + 32 * s + 8 * q + ii) * UDIM + uc]);
        wB1[s] = r;
    }

    if (tid < UDIM) {
        float s = be1[tid];
        const float* hi = &h[(b * NN + i) * HDIM];
#pragma unroll 8
        for (int k = 0; k < HDIM; ++k)
            s = fmaf(hi[k], We1[(1 + HDIM + k) * UDIM + tid], s);
        bias1L[tid] = s;              // be1 + h_i @ We1[65:129]
    }
    const float w0n  = We1[uc];
    const float b2n  = be2[uc];
    const float bqn  = bx1[uc];
    const float brn  = bx2[uc];
    const float winfc = Winf[uc];
    const float wx3c  = Wx3[uc];
    const float binf0 = binf[0], bx30 = bx3[0];
    const float xi0 = x[(b * NN + i) * 3 + 0];
    const float xi1 = x[(b * NN + i) * 3 + 1];
    const float xi2 = x[(b * NN + i) * 3 + 2];

    // ---- prologue: stage tile 0 ----
    {
        const int row = tid >> 4, c4 = (tid & 15) * 4;
        const float4 fv = *(const float4*)&h[(b * NN + row) * HDIM + c4];
        uint2 pv; pv.x = pk2(fv.x, fv.y); pv.y = pk2(fv.z, fv.w);
        *(uint2*)&F[row][c4] = pv;
        if (tid < JT) {
            float d0 = x[(b * NN + tid) * 3 + 0] - xi0;
            float d1 = x[(b * NN + tid) * 3 + 1] - xi1;
            float d2 = x[(b * NN + tid) * 3 + 2] - xi2;
            if (tid == i) { d0 = 0.f; d1 = 0.f; d2 = 0.f; }
            diffL[0][tid][0] = d0; diffL[0][tid][1] = d1; diffL[0][tid][2] = d2;
            normL[0][tid] = sqrtf(d0 * d0 + d1 * d1 + d2 * d2);
        }
    }
    __syncthreads();
    const float b1n = bias1L[uc];

    float mi = 0.f;
    float sh0 = 0.f, sh1 = 0.f, sh2 = 0.f;

    for (int t = 0; t < NTILE; ++t) {
        const int cur = t & 1, nxt = cur ^ 1;
        const int j0 = t * JT;
        const bool more = (t + 1 < NTILE);

        // ---- ph1: GEMM1 (F + norm + bias) -> P1 ----
        f32x4 acc[2];
#pragma unroll
        for (int m = 0; m < 2; ++m)
#pragma unroll
            for (int r = 0; r < 4; ++r)
                acc[m][r] = fmaf(normL[cur][jrb + 16 * m + 4 * q + r], w0n, b1n);
        {
            __builtin_amdgcn_s_setprio(1);
#pragma unroll
            for (int s = 0; s < 2; ++s) {
                const s16x8 a0 = *(const s16x8*)(&F[jrb + l15][32 * s + 8 * q]);
                const s16x8 a1 = *(const s16x8*)(&F[jrb + 16 + l15][32 * s + 8 * q]);
                acc[0] = MFMA(a0, wB1[s], acc[0]);
                acc[1] = MFMA(a1, wB1[s], acc[1]);
            }
            __builtin_amdgcn_s_setprio(0);
        }
        store1<true>(&P1[0][0], acc, q, uc, jrb);
        __syncthreads();

        // ---- ph2: GEMM2 -> macc (masked) -> P2; e-partials ----
        f32x4 macc[2];
#pragma unroll
        for (int m = 0; m < 2; ++m)
#pragma unroll
            for (int r = 0; r < 4; ++r) macc[m][r] = b2n;
        gemm_ldsB<4>(&P1[0][0], PP, W2L, uc, l15, q, jrb, macc);
#pragma unroll
        for (int m = 0; m < 2; ++m)
#pragma unroll
            for (int r = 0; r < 4; ++r)
                if (j0 + jrb + 16 * m + 4 * q + r == i) macc[m][r] = 0.f;
        store1<false>(&P2[0][0], macc, q, uc, jrb);
        {
            float pe[2][4];
#pragma unroll
            for (int m = 0; m < 2; ++m)
#pragma unroll
                for (int r = 0; r < 4; ++r) pe[m][r] = macc[m][r] * winfc;
#pragma unroll
            for (int d = 1; d < 16; d <<= 1)
#pragma unroll
                for (int m = 0; m < 2; ++m)
#pragma unroll
                    for (int r = 0; r < 4; ++r) pe[m][r] += __shfl_xor(pe[m][r], d);
            if (l15 == 0) {
#pragma unroll
                for (int m = 0; m < 2; ++m)
#pragma unroll
                    for (int r = 0; r < 4; ++r)
                        rpartE[ug][jrb + 16 * m + 4 * q + r] = pe[m][r];
            }
        }
        __syncthreads();

        // ---- ph3: stage t+1; e-final + m_i (macc dies); GEMM3 -> P1 ----
        if (more) {
            const int row = tid >> 4, c4 = (tid & 15) * 4;
            const float4 fv = *(const float4*)&h[(b * NN + j0 + JT + row) * HDIM + c4];
            float sxd0 = 0.f, sxd1 = 0.f, sxd2 = 0.f;
            if (tid < JT) {
                const int j = j0 + JT + tid;
                sxd0 = x[(b * NN + j) * 3 + 0] - xi0;
                sxd1 = x[(b * NN + j) * 3 + 1] - xi1;
                sxd2 = x[(b * NN + j) * 3 + 2] - xi2;
                if (j == i) { sxd0 = 0.f; sxd1 = 0.f; sxd2 = 0.f; }
            }
            // e-final + m_i while loads are in flight
            {
                float es = binf0;
#pragma unroll
                for (int g = 0; g < 8; ++g) es += rpartE[g][lane];
                const float ev = 1.f / (1.f + __expf(-es));
#pragma unroll
                for (int m = 0; m < 2; ++m)
#pragma unroll
                    for (int r = 0; r < 4; ++r) {
                        const float e = __shfl(ev, jrb + 16 * m + 4 * q + r);
                        mi = fmaf(macc[m][r], e, mi);
                    }
            }
            uint2 pv; pv.x = pk2(fv.x, fv.y); pv.y = pk2(fv.z, fv.w);
            *(uint2*)&F[row][c4] = pv;      // F[t] fully read in ph1 (2 barriers ago)
            if (tid < JT) {
                diffL[nxt][tid][0] = sxd0; diffL[nxt][tid][1] = sxd1; diffL[nxt][tid][2] = sxd2;
                normL[nxt][tid] = sqrtf(sxd0 * sxd0 + sxd1 * sxd1 + sxd2 * sxd2);
            }
        } else {
            float es = binf0;
#pragma unroll
            for (int g = 0; g < 8; ++g) es += rpartE[g][lane];
            const float ev = 1.f / (1.f + __expf(-es));
#pragma unroll
            for (int m = 0; m < 2; ++m)
#pragma unroll
                for (int r = 0; r < 4; ++r) {
                    const float e = __shfl(ev, jrb + 16 * m + 4 * q + r);
                    mi = fmaf(macc[m][r], e, mi);
                }
        }
        f32x4 qacc[2];
#pragma unroll
        for (int m = 0; m < 2; ++m)
#pragma unroll
            for (int r = 0; r < 4; ++r) qacc[m][r] = bqn;
        gemm_ldsB<4>(&P2[0][0], PP, W3L, uc, l15, q, jrb, qacc);
        store1<true>(&P1[0][0], qacc, q, uc, jrb);
        __syncthreads();

        // ---- ph4: GEMM4 -> racc; phi + shift per-thread (linear in cols) ----
        f32x4 racc[2];
#pragma unroll
        for (int m = 0; m < 2; ++m)
#pragma unroll
            for (int r = 0; r < 4; ++r) racc[m][r] = brn;
        gemm_ldsB<4>(&P1[0][0], PP, W4L, uc, l15, q, jrb, racc);
#pragma unroll
        for (int m = 0; m < 2; ++m)
#pragma unroll
            for (int r = 0; r < 4; ++r) {
                const int row = jrb + 16 * m + 4 * q + r;
                float p = eluf(racc[m][r]) * wx3c;
                if (ug == 0 && l15 == 0) p += bx30;   // bx3 once per row
                // row==i masked by diffL==0
                sh0 = fmaf(p, diffL[cur][row][0], sh0);
                sh1 = fmaf(p, diffL[cur][row][1], sh1);
                sh2 = fmaf(p, diffL[cur][row][2], sh2);
            }
        __syncthreads();
    }

    // ---- m_i: reduce over q-groups, 2-deep over jh ----
    {
        float v = mi;
        v += __shfl_xor(v, 16); v += __shfl_xor(v, 32);
        if (lane < 16) miL[jh][uc] = v;
    }
    // ---- shift: 64-lane butterfly per wave ----
    {
#pragma unroll
        for (int d = 1; d < 64; d <<= 1) {
            sh0 += __shfl_xor(sh0, d);
            sh1 += __shfl_xor(sh1, d);
            sh2 += __shfl_xor(sh2, d);
        }
        if (lane == 0) { shiftL[w][0] = sh0; shiftL[w][1] = sh1; shiftL[w][2] = sh2; }
    }
    __syncthreads();

    if (tid < UDIM) catL[tid] = miL[0][tid] + miL[1][tid];
    else if (tid < UDIM + HDIM) catL[tid] = h[(b * NN + i) * HDIM + (tid - UDIM)];
    if (tid < 3) {
        const float inv = 1.f / (float)(NN - 1);
        float s = 0.f;
#pragma unroll
        for (int p = 0; p < NW; ++p) s += shiftL[p][tid];
        out[(b * NN + i) * 3 + tid] = x[(b * NN + i) * 3 + tid] + s * inv;
    }
    __syncthreads();

    // ---- h-MLP epilogue (fp32) ----
    if (tid < UDIM) {
        float s = bh1[tid];
        for (int k = 0; k < UDIM + HDIM; ++k) s = fmaf(catL[k], Wh1[k * UDIM + tid], s);
        th1[tid] = eluf(s);
    }
    __syncthreads();
    if (tid < UDIM) {
        float s = bh2[tid];
        for (int k = 0; k < UDIM; ++k) s = fmaf(th1[k], Wh2[k * UDIM + tid], s);
        th2[tid] = s;
    }
    __syncthreads();
    if (tid < HDIM) {
        float s = bout[tid];
        for (int k = 0; k < UDIM; ++k) s = fmaf(th2[k], Wout[k * HDIM + tid], s);
        out[BB * NN * 3 + (b * NN + i) * HDIM + tid] = s;
    }
}

extern "C" void kernel_launch(void* const* d_in, const int* in_sizes, int n_in,
                              void* d_out, int out_size, void* d_ws, size_t ws_size,
                              hipStream_t stream) {
    const float* x    = (const float*)d_in[0];
    const float* h    = (const float*)d_in[1];
    const float* We1  = (const float*)d_in[2];
    const float* be1  = (const float*)d_in[3];
    const float* We2  = (const float*)d_in[4];
    const float* be2  = (const float*)d_in[5];
    const float* Winf = (const float*)d_in[6];
    const float* binf = (const float*)d_in[7];
    const float* Wx1  = (const float*)d_in[8];
    const float* bx1  = (const float*)d_in[9];
    const float* Wx2  = (const float*)d_in[10];
    const float* bx2  = (const float*)d_in[11];
    const float* Wx3  = (const float*)d_in[12];
    const float* bx3  = (const float*)d_in[13];
    const float* Wh1  = (const float*)d_in[14];
    const float* bh1  = (const float*)d_in[15];
    const float* Wh2  = (const float*)d_in[16];
    const float* bh2  = (const float*)d_in[17];
    const float* Wout = (const float*)d_in[18];
    const float* bout = (const float*)d_in[19];
    float* out = (float*)d_out;

    hipLaunchKernelGGL(egnn_lds16, dim3(BB * NN), dim3(1024), 0, stream,
                       x, h, We1, be1, We2, be2, Winf, binf, Wx1, bx1, Wx2, bx2,
                       Wx3, bx3, Wh1, bh1, Wh2, bh2, Wout, bout, out);
}